// Round 6
// baseline (428.440 us; speedup 1.0000x reference)
//
#include <hip/hip_runtime.h>
#include <hip/hip_bf16.h>
#include <math.h>

#define DEVI __device__ __forceinline__

typedef __attribute__((ext_vector_type(8))) short bf16x8;   // 8 bf16 in 4 VGPRs
typedef __attribute__((ext_vector_type(4))) float f32x4;

constexpr int Bn = 2;
constexpr int Tn = 2048;
constexpr int Cn = 2048;
constexpr int Hn = 16;
constexpr int Dn = 128;
constexpr int Mrows = Bn * Tn;   // 4096
constexpr int Nqkv = 3 * Cn;     // 6144
constexpr int BH = Bn * Hn;      // 32
constexpr int NKT = Cn / 32;     // 64 K-tiles per GEMM

DEVI f32x4 mfma16x16(bf16x8 a, bf16x8 b, f32x4 c) {
    return __builtin_amdgcn_mfma_f32_16x16x32_bf16(a, b, c, 0, 0, 0);
}

DEVI bf16x8 load8(const __hip_bfloat16* p) {
    return *(const bf16x8*)p;   // 16B aligned at all call sites
}

DEVI bf16x8 lds8c(const char* p, int byte_off) {
    return *(const bf16x8*)(p + byte_off);
}

DEVI short bf16bits(float f) {
    union { __hip_bfloat16 b; short s; } u;
    u.b = __float2bfloat16(f);
    return u.s;
}

// Async global->LDS 16B per lane (wave-uniform base + lane*16 dest).
typedef const __attribute__((address_space(1))) void* gas1_t;
typedef __attribute__((address_space(3))) void* las3_t;
DEVI void stage16(const __hip_bfloat16* g, __hip_bfloat16* l) {
    __builtin_amdgcn_global_load_lds((gas1_t)g, (las3_t)l, 16, 0, 0);
}

// ---------------------------------------------------------------------------
// fp32 -> bf16 bulk convert, 3 segments in ONE launch (dsts are contiguous
// in the workspace: xb | wab | wpb). 8 elements/thread.
// ---------------------------------------------------------------------------
__global__ __launch_bounds__(256) void cvt3_kernel(
    const float* __restrict__ s0,   // x      [n0]
    const float* __restrict__ s1,   // w_att  [n1]
    const float* __restrict__ s2,   // w_proj [n2]
    __hip_bfloat16* __restrict__ dst,   // xb (wab, wpb follow contiguously)
    long n0, long n1)
{
    const size_t i8 = ((size_t)blockIdx.x * 256 + threadIdx.x) * 8;
    const float* src;
    if ((long)i8 < n0)            src = s0 + i8;
    else if ((long)i8 < n0 + n1)  src = s1 + (i8 - n0);
    else                          src = s2 + (i8 - n0 - n1);
    const float4 a = *(const float4*)(src);
    const float4 b = *(const float4*)(src + 4);
    union { bf16x8 v; __hip_bfloat16 h[8]; } u;
    u.h[0] = __float2bfloat16(a.x); u.h[1] = __float2bfloat16(a.y);
    u.h[2] = __float2bfloat16(a.z); u.h[3] = __float2bfloat16(a.w);
    u.h[4] = __float2bfloat16(b.x); u.h[5] = __float2bfloat16(b.y);
    u.h[6] = __float2bfloat16(b.z); u.h[7] = __float2bfloat16(b.w);
    *(bf16x8*)(dst + i8) = u.v;
}

// ---------------------------------------------------------------------------
// QKV GEMM, pure bf16, m97-style global_load_lds staging, double-buffered.
// (Round-0 version, 163 us — confirmed 4x. 8-phase abandoned this session.)
// ---------------------------------------------------------------------------
__global__ __launch_bounds__(256) void qkv_gemm_kernel(
    const __hip_bfloat16* __restrict__ xb,
    const __hip_bfloat16* __restrict__ wab,
    const float* __restrict__ bias,
    __hip_bfloat16* __restrict__ Qo,
    __hip_bfloat16* __restrict__ Ko,
    __hip_bfloat16* __restrict__ Vt)
{
    __shared__ __align__(16) __hip_bfloat16 As[2][128 * 32];  // 2 x 8 KB
    __shared__ __align__(16) __hip_bfloat16 Bs[2][128 * 32];  // 2 x 8 KB
    const int tid  = threadIdx.x;
    const int lane = tid & 63;
    const int wid  = tid >> 6;
    const int quad = lane >> 4;
    const int l16  = lane & 15;
    const int bm = blockIdx.y * 128;
    const int bn = blockIdx.x * 128;
    const int wm = (wid >> 1) * 64;
    const int wn = (wid & 1) * 64;

    const int lr = lane >> 2;          // 0..15 row within 16-row chunk
    const int lc = (lane & 3) * 8;     // 0,8,16,24 elements within row
    const int r0 = 32 * wid;           // this wave's staging rows
    const __hip_bfloat16* Ag0 = xb  + (size_t)(bm + r0 + lr) * Cn + lc;
    const __hip_bfloat16* Ag1 = xb  + (size_t)(bm + r0 + 16 + lr) * Cn + lc;
    const __hip_bfloat16* Bg0 = wab + (size_t)(bn + r0 + lr) * Cn + lc;
    const __hip_bfloat16* Bg1 = wab + (size_t)(bn + r0 + 16 + lr) * Cn + lc;
    const int lbase0 = r0 * 32 + lane * 8;         // lds element offsets
    const int lbase1 = (r0 + 16) * 32 + lane * 8;

    const f32x4 zero = {0.f, 0.f, 0.f, 0.f};
    f32x4 acc[4][4];
#pragma unroll
    for (int i = 0; i < 4; ++i)
#pragma unroll
        for (int j = 0; j < 4; ++j) acc[i][j] = zero;

    stage16(Ag0, &As[0][lbase0]);
    stage16(Ag1, &As[0][lbase1]);
    stage16(Bg0, &Bs[0][lbase0]);
    stage16(Bg1, &Bs[0][lbase1]);
    __syncthreads();

    for (int kt = 0; kt < NKT; ++kt) {
        const int cur = kt & 1;
        if (kt + 1 < NKT) {
            const int kn = (kt + 1) * 32;
            stage16(Ag0 + kn, &As[cur ^ 1][lbase0]);
            stage16(Ag1 + kn, &As[cur ^ 1][lbase1]);
            stage16(Bg0 + kn, &Bs[cur ^ 1][lbase0]);
            stage16(Bg1 + kn, &Bs[cur ^ 1][lbase1]);
        }
        bf16x8 af[4], bfr[4];
#pragma unroll
        for (int i = 0; i < 4; ++i)
            af[i] = load8(&As[cur][(wm + i * 16 + l16) * 32 + quad * 8]);
#pragma unroll
        for (int j = 0; j < 4; ++j)
            bfr[j] = load8(&Bs[cur][(wn + j * 16 + l16) * 32 + quad * 8]);
#pragma unroll
        for (int i = 0; i < 4; ++i)
#pragma unroll
            for (int j = 0; j < 4; ++j)
                acc[i][j] = mfma16x16(af[i], bfr[j], acc[i][j]);
        __syncthreads();   // drains prefetch (vmcnt) + cur reads
    }

#pragma unroll
    for (int j = 0; j < 4; ++j) {
        const int n = bn + wn + j * 16 + l16;
        const float bv = bias[n];
        const int sel = n >> 11;      // 0=q, 1=k, 2=v
        const int c   = n & 2047;
        const int h   = c >> 7;
        const int d   = c & 127;
#pragma unroll
        for (int i = 0; i < 4; ++i) {
#pragma unroll
            for (int r = 0; r < 4; ++r) {
                const int m = bm + wm + i * 16 + quad * 4 + r;
                const int b = m >> 11;
                const int t = m & 2047;
                const int bh = b * Hn + h;
                const __hip_bfloat16 hv = __float2bfloat16(acc[i][j][r] + bv);
                if (sel == 0)      Qo[((size_t)bh * Tn + t) * Dn + d] = hv;
                else if (sel == 1) Ko[((size_t)bh * Tn + t) * Dn + d] = hv;
                else               Vt[((size_t)bh * Dn + d) * Tn + t] = hv;
            }
        }
    }
}

// ---------------------------------------------------------------------------
// RoPE in place on Q and K.
// ---------------------------------------------------------------------------
__global__ __launch_bounds__(256) void rope_kernel(
    __hip_bfloat16* __restrict__ Qo,
    __hip_bfloat16* __restrict__ Ko)
{
    const size_t idx = (size_t)blockIdx.x * blockDim.x + threadIdx.x; // BH*T*64
    const int d2 = (int)(idx & 63);
    const int t  = (int)((idx >> 6) & (size_t)(Tn - 1));
    const float inv = exp2f(-(float)d2 * (1.0f / 64.0f) * 13.287712379549449f);
    float sn, cs;
    sincosf((float)t * inv, &sn, &cs);
    const size_t base = (idx >> 6) * (size_t)Dn + (size_t)(2 * d2);
    {
        const float a = __bfloat162float(Qo[base]);
        const float b = __bfloat162float(Qo[base + 1]);
        Qo[base]     = __float2bfloat16(a * cs - b * sn);
        Qo[base + 1] = __float2bfloat16(a * sn + b * cs);
    }
    {
        const float a = __bfloat162float(Ko[base]);
        const float b = __bfloat162float(Ko[base + 1]);
        Ko[base]     = __float2bfloat16(a * cs - b * sn);
        Ko[base + 1] = __float2bfloat16(a * sn + b * cs);
    }
}

// ---------------------------------------------------------------------------
// Flash attention (causal). THIS ROUND: QBLK/wave 16 -> 32 (block covers 128
// q-rows, grid 1024 -> 512). Halves total K/V staging traffic (~540->270 MB)
// and doubles MFMA per staged byte; each K-fragment ds_read now feeds TWO
// MFMAs (row-fragments f=0,1). P stays a 16-row wave-private buffer,
// processed per fragment, so LDS stays 73 KB -> 2 blocks/CU.
// Load balance: 512 blocks == resident slots; group g<8 -> qblk 15-g
// (heavy), g>=8 -> qblk g-8 (light) => round-robin pairing sums to a
// constant 36 tiles/CU.
// Staging/swizzles identical to round 5 (verified):
//   K tile [64][128] bf16: col-seg(16B) ^= row&15. Conflict-free.
//   V^T tile [128][64] bf16: col-seg ^= row&7 (vkey is the FULL col offset).
// ---------------------------------------------------------------------------
__global__ __launch_bounds__(256, 2) void flash_kernel(
    const __hip_bfloat16* __restrict__ Qo,
    const __hip_bfloat16* __restrict__ Ko,
    const __hip_bfloat16* __restrict__ Vt,
    __hip_bfloat16* __restrict__ Y)
{
    __shared__ __align__(16) short Ks[2][64 * 128];  // 2 x 16 KB, swizzled
    __shared__ __align__(16) short Vs[2][128 * 64];  // 2 x 16 KB, swizzled
    __shared__ __align__(16) short Ps[4][16 * 72];   // 9 KB wave-private P
    const int tid  = threadIdx.x;
    const int lane = tid & 63;
    const int wid  = tid >> 6;
    const int quad = lane >> 4;
    const int l16  = lane & 15;
    const int bh   = blockIdx.x & (BH - 1);
    const int g    = blockIdx.x >> 5;                // 0..15
    const int qblk = (g < 8) ? (15 - g) : (g - 8);   // heavy/light pairing
    const int q0w  = qblk * 128 + wid * 32;
    const int nkt  = 2 * qblk + 2;                   // 64-wide K/V tiles

    const __hip_bfloat16* Qb = Qo + (size_t)bh * Tn * Dn;
    const __hip_bfloat16* Kg = Ko + (size_t)bh * Tn * Dn;   // [t][d]
    const __hip_bfloat16* Vg = Vt + (size_t)bh * Dn * Tn;   // [d][t]
    short* P = &Ps[wid][0];

    // --- staging geometry (dest seg = tid + c*256, c = 0..3; 16B segs) ---
    const int kr  = tid >> 4;
    const int ksl = (tid & 15) ^ kr;
    const __hip_bfloat16* KgA = Kg + (size_t)kr * Dn + ksl * 8;
    const int vr  = tid >> 3;
    const int vsl = (tid & 7) ^ (vr & 7);
    const __hip_bfloat16* VgA = Vg + (size_t)vr * Tn + vsl * 8;

    // --- swizzled read offsets (bytes), kt-invariant ---
    int koff[4];
#pragma unroll
    for (int ks = 0; ks < 4; ++ks)
        koff[ks] = l16 * 256 + ((((ks * 4 + quad) ^ l16) & 15) << 4);
    int vkey[2];
#pragma unroll
    for (int h = 0; h < 2; ++h)
        vkey[h] = (((h * 4 + quad) ^ (l16 & 7)) << 4);

    bf16x8 qf[2][4];
#pragma unroll
    for (int f = 0; f < 2; ++f)
#pragma unroll
        for (int ks = 0; ks < 4; ++ks)
            qf[f][ks] = load8(Qb + (size_t)(q0w + f * 16 + l16) * Dn + ks * 32 + quad * 8);

    const f32x4 zero = {0.f, 0.f, 0.f, 0.f};
    f32x4 o[2][8];
#pragma unroll
    for (int f = 0; f < 2; ++f)
#pragma unroll
        for (int j = 0; j < 8; ++j) o[f][j] = zero;
    float lpart[2][4] = {{0.f, 0.f, 0.f, 0.f}, {0.f, 0.f, 0.f, 0.f}};
    const float scale2 = 0.12751743430267602f;   // log2(e)/sqrt(128)

    // Prologue: stage tile 0 into buffer 0 (8 calls: 4 K + 4 V).
#pragma unroll
    for (int c = 0; c < 4; ++c) {
        stage16(KgA + (size_t)(c * 16) * Dn, (__hip_bfloat16*)&Ks[0][c * 2048 + tid * 8]);
        stage16(VgA + (size_t)(c * 32) * Tn, (__hip_bfloat16*)&Vs[0][c * 2048 + tid * 8]);
    }
    __syncthreads();

    for (int kt = 0; kt < nkt; ++kt) {
        const int cur = kt & 1;
        if (kt + 1 < nkt) {
            const int kb2 = (kt + 1) * 64;
            const int nxt = cur ^ 1;
#pragma unroll
            for (int c = 0; c < 4; ++c) {
                stage16(KgA + (size_t)(kb2 + c * 16) * Dn,
                        (__hip_bfloat16*)&Ks[nxt][c * 2048 + tid * 8]);
                stage16(VgA + (size_t)(c * 32) * Tn + kb2,
                        (__hip_bfloat16*)&Vs[nxt][c * 2048 + tid * 8]);
            }
        }
        const int kb = kt * 64;
        if (kb <= q0w + 31) {
            f32x4 sc[2][4];
#pragma unroll
            for (int f = 0; f < 2; ++f)
#pragma unroll
                for (int gg = 0; gg < 4; ++gg) sc[f][gg] = zero;
#pragma unroll
            for (int ks = 0; ks < 4; ++ks) {
#pragma unroll
                for (int gg = 0; gg < 4; ++gg) {
                    bf16x8 kf = lds8c((const char*)&Ks[cur][0], koff[ks] + gg * 4096);
                    sc[0][gg] = mfma16x16(qf[0][ks], kf, sc[0][gg]);
                    sc[1][gg] = mfma16x16(qf[1][ks], kf, sc[1][gg]);
                }
            }
#pragma unroll
            for (int f = 0; f < 2; ++f) {
                const int rowbase = q0w + f * 16;
                if (kb + 63 <= rowbase) {
#pragma unroll
                    for (int gg = 0; gg < 4; ++gg)
#pragma unroll
                        for (int r = 0; r < 4; ++r) {
                            const float p = exp2f(sc[f][gg][r] * scale2);
                            lpart[f][r] += p;
                            P[(quad * 4 + r) * 72 + gg * 16 + l16] = bf16bits(p);
                        }
                } else {
#pragma unroll
                    for (int gg = 0; gg < 4; ++gg)
#pragma unroll
                        for (int r = 0; r < 4; ++r) {
                            const int row = rowbase + quad * 4 + r;
                            const float a = (kb + gg * 16 + l16 <= row)
                                            ? sc[f][gg][r] * scale2 : -INFINITY;
                            const float p = exp2f(a);
                            lpart[f][r] += p;
                            P[(quad * 4 + r) * 72 + gg * 16 + l16] = bf16bits(p);
                        }
                }
                __builtin_amdgcn_sched_barrier(0);
                bf16x8 af0 = *(const bf16x8*)(P + l16 * 72 + quad * 8);
                bf16x8 af1 = *(const bf16x8*)(P + l16 * 72 + 32 + quad * 8);
#pragma unroll
                for (int j = 0; j < 8; ++j) {
                    bf16x8 vf0 = lds8c((const char*)&Vs[cur][0], (j * 16 + l16) * 128 + vkey[0]);
                    bf16x8 vf1 = lds8c((const char*)&Vs[cur][0], (j * 16 + l16) * 128 + vkey[1]);
                    o[f][j] = mfma16x16(af0, vf0, o[f][j]);
                    o[f][j] = mfma16x16(af1, vf1, o[f][j]);
                }
                __builtin_amdgcn_sched_barrier(0);
            }
        }
        __syncthreads();   // drains prefetch vmcnt + cur LDS reads
    }

    const int b = bh >> 4;
    const int h = bh & 15;
#pragma unroll
    for (int f = 0; f < 2; ++f) {
        float invl[4];
#pragma unroll
        for (int r = 0; r < 4; ++r) {
            float s = lpart[f][r];
#pragma unroll
            for (int off = 1; off < 16; off <<= 1)
                s += __shfl_xor(s, off, 16);
            invl[r] = 1.0f / s;
        }
#pragma unroll
        for (int j = 0; j < 8; ++j) {
#pragma unroll
            for (int r = 0; r < 4; ++r) {
                const int t = q0w + f * 16 + quad * 4 + r;
                Y[((size_t)b * Tn + t) * Cn + h * Dn + j * 16 + l16] =
                    __float2bfloat16(o[f][j][r] * invl[r]);
            }
        }
    }
}

// ---------------------------------------------------------------------------
// Output projection, pure bf16 inputs, global_load_lds staging, dbuf.
// out = Yb @ wpb^T + b_proj (fp32 out).
// ---------------------------------------------------------------------------
__global__ __launch_bounds__(256) void proj_gemm_kernel(
    const __hip_bfloat16* __restrict__ Yb,
    const __hip_bfloat16* __restrict__ wpb,
    const float* __restrict__ bias,
    float* __restrict__ out)
{
    __shared__ __align__(16) __hip_bfloat16 As[2][128 * 32];
    __shared__ __align__(16) __hip_bfloat16 Bs[2][128 * 32];
    const int tid  = threadIdx.x;
    const int lane = tid & 63;
    const int wid  = tid >> 6;
    const int quad = lane >> 4;
    const int l16  = lane & 15;
    const int bm = blockIdx.y * 128;
    const int bn = blockIdx.x * 128;
    const int wm = (wid >> 1) * 64;
    const int wn = (wid & 1) * 64;

    const int lr = lane >> 2;
    const int lc = (lane & 3) * 8;
    const int r0 = 32 * wid;
    const __hip_bfloat16* Ag0 = Yb  + (size_t)(bm + r0 + lr) * Cn + lc;
    const __hip_bfloat16* Ag1 = Yb  + (size_t)(bm + r0 + 16 + lr) * Cn + lc;
    const __hip_bfloat16* Bg0 = wpb + (size_t)(bn + r0 + lr) * Cn + lc;
    const __hip_bfloat16* Bg1 = wpb + (size_t)(bn + r0 + 16 + lr) * Cn + lc;
    const int lbase0 = r0 * 32 + lane * 8;
    const int lbase1 = (r0 + 16) * 32 + lane * 8;

    const f32x4 zero = {0.f, 0.f, 0.f, 0.f};
    f32x4 acc[4][4];
#pragma unroll
    for (int i = 0; i < 4; ++i)
#pragma unroll
        for (int j = 0; j < 4; ++j) acc[i][j] = zero;

    stage16(Ag0, &As[0][lbase0]);
    stage16(Ag1, &As[0][lbase1]);
    stage16(Bg0, &Bs[0][lbase0]);
    stage16(Bg1, &Bs[0][lbase1]);
    __syncthreads();

    for (int kt = 0; kt < NKT; ++kt) {
        const int cur = kt & 1;
        if (kt + 1 < NKT) {
            const int kn = (kt + 1) * 32;
            stage16(Ag0 + kn, &As[cur ^ 1][lbase0]);
            stage16(Ag1 + kn, &As[cur ^ 1][lbase1]);
            stage16(Bg0 + kn, &Bs[cur ^ 1][lbase0]);
            stage16(Bg1 + kn, &Bs[cur ^ 1][lbase1]);
        }
        bf16x8 af[4], bfr[4];
#pragma unroll
        for (int i = 0; i < 4; ++i)
            af[i] = load8(&As[cur][(wm + i * 16 + l16) * 32 + quad * 8]);
#pragma unroll
        for (int j = 0; j < 4; ++j)
            bfr[j] = load8(&Bs[cur][(wn + j * 16 + l16) * 32 + quad * 8]);
#pragma unroll
        for (int i = 0; i < 4; ++i)
#pragma unroll
            for (int j = 0; j < 4; ++j)
                acc[i][j] = mfma16x16(af[i], bfr[j], acc[i][j]);
        __syncthreads();
    }

#pragma unroll
    for (int j = 0; j < 4; ++j) {
        const int n = bn + wn + j * 16 + l16;
        const float bv = bias[n];
#pragma unroll
        for (int i = 0; i < 4; ++i) {
#pragma unroll
            for (int r = 0; r < 4; ++r) {
                const int m = bm + wm + i * 16 + quad * 4 + r;
                out[(size_t)m * Cn + n] = acc[i][j][r] + bv;   // fp32 store
            }
        }
    }
}

// ---------------------------------------------------------------------------
extern "C" void kernel_launch(void* const* d_in, const int* in_sizes, int n_in,
                              void* d_out, int out_size, void* d_ws, size_t ws_size,
                              hipStream_t stream)
{
    // All five inputs AND the output are fp32 (verified round 5).
    const float* x      = (const float*)d_in[0];
    const float* w_att  = (const float*)d_in[1];
    const float* b_att  = (const float*)d_in[2];
    const float* w_proj = (const float*)d_in[3];
    const float* b_proj = (const float*)d_in[4];
    float* out = (float*)d_out;

    // Workspace layout (bf16 elements), ~96 MB total:
    //   [Qo per][Ko per][Vt per][xb per | Yb alias][wab 12.58M][wpb 4.19M]
    // xb|wab|wpb are CONTIGUOUS -> single cvt3 launch writes all three.
    const size_t per  = (size_t)BH * Tn * Dn;        // 8,388,608
    const size_t wabN = (size_t)Nqkv * Cn;           // 12,582,912
    __hip_bfloat16* Qo  = (__hip_bfloat16*)d_ws;
    __hip_bfloat16* Ko  = Qo + per;
    __hip_bfloat16* Vt  = Ko + per;
    __hip_bfloat16* xb  = Vt + per;
    __hip_bfloat16* wab = xb + per;
    __hip_bfloat16* wpb = wab + wabN;
    __hip_bfloat16* Yb  = xb;                        // alias (see above)

    const long n0 = (long)Mrows * Cn;                // 8,388,608
    const long n1 = (long)Nqkv * Cn;                 // 12,582,912
    const long n2 = (long)Cn * Cn;                   // 4,194,304

    dim3 blk(256);
    cvt3_kernel<<<dim3((unsigned)((n0 + n1 + n2) / 2048)), blk, 0, stream>>>(
        x, w_att, w_proj, xb, n0, n1);
    qkv_gemm_kernel<<<dim3(Nqkv / 128, Mrows / 128), blk, 0, stream>>>(
        xb, wab, b_att, Qo, Ko, Vt);
    rope_kernel<<<dim3((BH * Tn * 64) / 256), blk, 0, stream>>>(Qo, Ko);
    flash_kernel<<<dim3((Tn / 128) * BH), blk, 0, stream>>>(Qo, Ko, Vt, Yb);
    proj_gemm_kernel<<<dim3(Cn / 128, Mrows / 128), blk, 0, stream>>>(
        Yb, wpb, b_proj, out);
}

// Round 7
// 413.280 us; speedup vs baseline: 1.0367x; 1.0367x over previous
//
#include <hip/hip_runtime.h>
#include <hip/hip_bf16.h>
#include <math.h>

#define DEVI __device__ __forceinline__

typedef __attribute__((ext_vector_type(8))) short bf16x8;   // 8 bf16 in 4 VGPRs
typedef __attribute__((ext_vector_type(4))) float f32x4;

constexpr int Bn = 2;
constexpr int Tn = 2048;
constexpr int Cn = 2048;
constexpr int Hn = 16;
constexpr int Dn = 128;
constexpr int Mrows = Bn * Tn;   // 4096
constexpr int Nqkv = 3 * Cn;     // 6144
constexpr int BH = Bn * Hn;      // 32
constexpr int NKT = Cn / 32;     // 64 K-tiles per GEMM

DEVI f32x4 mfma16x16(bf16x8 a, bf16x8 b, f32x4 c) {
    return __builtin_amdgcn_mfma_f32_16x16x32_bf16(a, b, c, 0, 0, 0);
}

DEVI bf16x8 load8(const __hip_bfloat16* p) {
    return *(const bf16x8*)p;   // 16B aligned at all call sites
}

DEVI bf16x8 lds8c(const char* p, int byte_off) {
    return *(const bf16x8*)(p + byte_off);
}

DEVI short bf16bits(float f) {
    union { __hip_bfloat16 b; short s; } u;
    u.b = __float2bfloat16(f);
    return u.s;
}

// Async global->LDS 16B per lane (wave-uniform base + lane*16 dest).
typedef const __attribute__((address_space(1))) void* gas1_t;
typedef __attribute__((address_space(3))) void* las3_t;
DEVI void stage16(const __hip_bfloat16* g, __hip_bfloat16* l) {
    __builtin_amdgcn_global_load_lds((gas1_t)g, (las3_t)l, 16, 0, 0);
}

// ---------------------------------------------------------------------------
// fp32 -> bf16 bulk convert, 3 segments in ONE launch (dsts are contiguous
// in the workspace: xb | wab | wpb). 8 elements/thread. (Kept from R6; this
// round attributes it: flash reverted to R5, so total ≈ 420 confirms cvt3
// neutral.)
// ---------------------------------------------------------------------------
__global__ __launch_bounds__(256) void cvt3_kernel(
    const float* __restrict__ s0,   // x      [n0]
    const float* __restrict__ s1,   // w_att  [n1]
    const float* __restrict__ s2,   // w_proj [n2]
    __hip_bfloat16* __restrict__ dst,   // xb (wab, wpb follow contiguously)
    long n0, long n1)
{
    const size_t i8 = ((size_t)blockIdx.x * 256 + threadIdx.x) * 8;
    const float* src;
    if ((long)i8 < n0)            src = s0 + i8;
    else if ((long)i8 < n0 + n1)  src = s1 + (i8 - n0);
    else                          src = s2 + (i8 - n0 - n1);
    const float4 a = *(const float4*)(src);
    const float4 b = *(const float4*)(src + 4);
    union { bf16x8 v; __hip_bfloat16 h[8]; } u;
    u.h[0] = __float2bfloat16(a.x); u.h[1] = __float2bfloat16(a.y);
    u.h[2] = __float2bfloat16(a.z); u.h[3] = __float2bfloat16(a.w);
    u.h[4] = __float2bfloat16(b.x); u.h[5] = __float2bfloat16(b.y);
    u.h[6] = __float2bfloat16(b.z); u.h[7] = __float2bfloat16(b.w);
    *(bf16x8*)(dst + i8) = u.v;
}

// ---------------------------------------------------------------------------
// QKV GEMM, pure bf16, m97-style global_load_lds staging, double-buffered.
// (Round-0 version, 163 us — confirmed 5x. 8-phase abandoned this session.)
// ---------------------------------------------------------------------------
__global__ __launch_bounds__(256) void qkv_gemm_kernel(
    const __hip_bfloat16* __restrict__ xb,
    const __hip_bfloat16* __restrict__ wab,
    const float* __restrict__ bias,
    __hip_bfloat16* __restrict__ Qo,
    __hip_bfloat16* __restrict__ Ko,
    __hip_bfloat16* __restrict__ Vt)
{
    __shared__ __align__(16) __hip_bfloat16 As[2][128 * 32];  // 2 x 8 KB
    __shared__ __align__(16) __hip_bfloat16 Bs[2][128 * 32];  // 2 x 8 KB
    const int tid  = threadIdx.x;
    const int lane = tid & 63;
    const int wid  = tid >> 6;
    const int quad = lane >> 4;
    const int l16  = lane & 15;
    const int bm = blockIdx.y * 128;
    const int bn = blockIdx.x * 128;
    const int wm = (wid >> 1) * 64;
    const int wn = (wid & 1) * 64;

    const int lr = lane >> 2;          // 0..15 row within 16-row chunk
    const int lc = (lane & 3) * 8;     // 0,8,16,24 elements within row
    const int r0 = 32 * wid;           // this wave's staging rows
    const __hip_bfloat16* Ag0 = xb  + (size_t)(bm + r0 + lr) * Cn + lc;
    const __hip_bfloat16* Ag1 = xb  + (size_t)(bm + r0 + 16 + lr) * Cn + lc;
    const __hip_bfloat16* Bg0 = wab + (size_t)(bn + r0 + lr) * Cn + lc;
    const __hip_bfloat16* Bg1 = wab + (size_t)(bn + r0 + 16 + lr) * Cn + lc;
    const int lbase0 = r0 * 32 + lane * 8;         // lds element offsets
    const int lbase1 = (r0 + 16) * 32 + lane * 8;

    const f32x4 zero = {0.f, 0.f, 0.f, 0.f};
    f32x4 acc[4][4];
#pragma unroll
    for (int i = 0; i < 4; ++i)
#pragma unroll
        for (int j = 0; j < 4; ++j) acc[i][j] = zero;

    stage16(Ag0, &As[0][lbase0]);
    stage16(Ag1, &As[0][lbase1]);
    stage16(Bg0, &Bs[0][lbase0]);
    stage16(Bg1, &Bs[0][lbase1]);
    __syncthreads();

    for (int kt = 0; kt < NKT; ++kt) {
        const int cur = kt & 1;
        if (kt + 1 < NKT) {
            const int kn = (kt + 1) * 32;
            stage16(Ag0 + kn, &As[cur ^ 1][lbase0]);
            stage16(Ag1 + kn, &As[cur ^ 1][lbase1]);
            stage16(Bg0 + kn, &Bs[cur ^ 1][lbase0]);
            stage16(Bg1 + kn, &Bs[cur ^ 1][lbase1]);
        }
        bf16x8 af[4], bfr[4];
#pragma unroll
        for (int i = 0; i < 4; ++i)
            af[i] = load8(&As[cur][(wm + i * 16 + l16) * 32 + quad * 8]);
#pragma unroll
        for (int j = 0; j < 4; ++j)
            bfr[j] = load8(&Bs[cur][(wn + j * 16 + l16) * 32 + quad * 8]);
#pragma unroll
        for (int i = 0; i < 4; ++i)
#pragma unroll
            for (int j = 0; j < 4; ++j)
                acc[i][j] = mfma16x16(af[i], bfr[j], acc[i][j]);
        __syncthreads();   // drains prefetch (vmcnt) + cur reads
    }

#pragma unroll
    for (int j = 0; j < 4; ++j) {
        const int n = bn + wn + j * 16 + l16;
        const float bv = bias[n];
        const int sel = n >> 11;      // 0=q, 1=k, 2=v
        const int c   = n & 2047;
        const int h   = c >> 7;
        const int d   = c & 127;
#pragma unroll
        for (int i = 0; i < 4; ++i) {
#pragma unroll
            for (int r = 0; r < 4; ++r) {
                const int m = bm + wm + i * 16 + quad * 4 + r;
                const int b = m >> 11;
                const int t = m & 2047;
                const int bh = b * Hn + h;
                const __hip_bfloat16 hv = __float2bfloat16(acc[i][j][r] + bv);
                if (sel == 0)      Qo[((size_t)bh * Tn + t) * Dn + d] = hv;
                else if (sel == 1) Ko[((size_t)bh * Tn + t) * Dn + d] = hv;
                else               Vt[((size_t)bh * Dn + d) * Tn + t] = hv;
            }
        }
    }
}

// ---------------------------------------------------------------------------
// RoPE in place on Q and K.
// ---------------------------------------------------------------------------
__global__ __launch_bounds__(256) void rope_kernel(
    __hip_bfloat16* __restrict__ Qo,
    __hip_bfloat16* __restrict__ Ko)
{
    const size_t idx = (size_t)blockIdx.x * blockDim.x + threadIdx.x; // BH*T*64
    const int d2 = (int)(idx & 63);
    const int t  = (int)((idx >> 6) & (size_t)(Tn - 1));
    const float inv = exp2f(-(float)d2 * (1.0f / 64.0f) * 13.287712379549449f);
    float sn, cs;
    sincosf((float)t * inv, &sn, &cs);
    const size_t base = (idx >> 6) * (size_t)Dn + (size_t)(2 * d2);
    {
        const float a = __bfloat162float(Qo[base]);
        const float b = __bfloat162float(Qo[base + 1]);
        Qo[base]     = __float2bfloat16(a * cs - b * sn);
        Qo[base + 1] = __float2bfloat16(a * sn + b * cs);
    }
    {
        const float a = __bfloat162float(Ko[base]);
        const float b = __bfloat162float(Ko[base + 1]);
        Ko[base]     = __float2bfloat16(a * cs - b * sn);
        Ko[base + 1] = __float2bfloat16(a * sn + b * cs);
    }
}

// ---------------------------------------------------------------------------
// Flash attention (causal), KVBLK=64, QBLK=16/wave — REVERTED to the R5
// version verbatim (best measured flash; R6's QBLK=32 serialized two
// row-fragments through the same P buffer and regressed ~8 us; flash is
// critical-path-bound in softmax/PV, not staging-traffic-bound).
//   K tile [64][128] bf16: col-seg(16B) ^= row&15. Conflict-free.
//   V^T tile [128][64] bf16: col-seg ^= row&7 (vkey is the FULL col offset).
// LDS: Ks 32KB + Vs 32KB + Ps 9KB = 73KB -> 2 blocks/CU.
// ---------------------------------------------------------------------------
__global__ __launch_bounds__(256) void flash_kernel(
    const __hip_bfloat16* __restrict__ Qo,
    const __hip_bfloat16* __restrict__ Ko,
    const __hip_bfloat16* __restrict__ Vt,
    __hip_bfloat16* __restrict__ Y)
{
    __shared__ __align__(16) short Ks[2][64 * 128];  // 2 x 16 KB, swizzled
    __shared__ __align__(16) short Vs[2][128 * 64];  // 2 x 16 KB, swizzled
    __shared__ __align__(16) short Ps[4][16 * 72];   // 9 KB wave-private P
    const int tid  = threadIdx.x;
    const int lane = tid & 63;
    const int wid  = tid >> 6;
    const int quad = lane >> 4;
    const int l16  = lane & 15;
    const int bh   = blockIdx.x & (BH - 1);
    const int qblk = 31 - (blockIdx.x >> 5);         // heavy q-blocks first
    const int q0w  = qblk * 64 + wid * 16;
    const int nkt  = qblk + 1;                       // 64-wide K/V tiles

    const __hip_bfloat16* Qb = Qo + (size_t)bh * Tn * Dn;
    const __hip_bfloat16* Kg = Ko + (size_t)bh * Tn * Dn;   // [t][d]
    const __hip_bfloat16* Vg = Vt + (size_t)bh * Dn * Tn;   // [d][t]
    short* P = &Ps[wid][0];

    // --- staging geometry (dest seg = tid + c*256, c = 0..3; 16B segs) ---
    const int kr  = tid >> 4;
    const int ksl = (tid & 15) ^ kr;
    const __hip_bfloat16* KgA = Kg + (size_t)kr * Dn + ksl * 8;
    const int vr  = tid >> 3;
    const int vsl = (tid & 7) ^ (vr & 7);
    const __hip_bfloat16* VgA = Vg + (size_t)vr * Tn + vsl * 8;

    // --- swizzled read offsets (bytes), kt-invariant ---
    int koff[4];
#pragma unroll
    for (int ks = 0; ks < 4; ++ks)
        koff[ks] = l16 * 256 + ((((ks * 4 + quad) ^ l16) & 15) << 4);
    int vkey[2];
#pragma unroll
    for (int h = 0; h < 2; ++h)
        vkey[h] = (((h * 4 + quad) ^ (l16 & 7)) << 4);

    bf16x8 qf[4];
#pragma unroll
    for (int ks = 0; ks < 4; ++ks)
        qf[ks] = load8(Qb + (size_t)(q0w + l16) * Dn + ks * 32 + quad * 8);

    const f32x4 zero = {0.f, 0.f, 0.f, 0.f};
    f32x4 o[8];
#pragma unroll
    for (int j = 0; j < 8; ++j) o[j] = zero;
    float lpart[4] = {0.f, 0.f, 0.f, 0.f};
    const float scale2 = 0.12751743430267602f;   // log2(e)/sqrt(128)

    // Prologue: stage tile 0 into buffer 0 (8 calls: 4 K + 4 V).
#pragma unroll
    for (int c = 0; c < 4; ++c) {
        stage16(KgA + (size_t)(c * 16) * Dn, (__hip_bfloat16*)&Ks[0][c * 2048 + tid * 8]);
        stage16(VgA + (size_t)(c * 32) * Tn, (__hip_bfloat16*)&Vs[0][c * 2048 + tid * 8]);
    }
    __syncthreads();

    for (int kt = 0; kt < nkt; ++kt) {
        const int cur = kt & 1;
        if (kt + 1 < nkt) {
            const int kb2 = (kt + 1) * 64;
            const int nxt = cur ^ 1;
#pragma unroll
            for (int c = 0; c < 4; ++c) {
                stage16(KgA + (size_t)(kb2 + c * 16) * Dn,
                        (__hip_bfloat16*)&Ks[nxt][c * 2048 + tid * 8]);
                stage16(VgA + (size_t)(c * 32) * Tn + kb2,
                        (__hip_bfloat16*)&Vs[nxt][c * 2048 + tid * 8]);
            }
        }
        const int kb = kt * 64;
        if (kb <= q0w + 15) {
            f32x4 sc[4];
#pragma unroll
            for (int g = 0; g < 4; ++g) sc[g] = zero;
#pragma unroll
            for (int ks = 0; ks < 4; ++ks) {
#pragma unroll
                for (int g = 0; g < 4; ++g) {
                    bf16x8 kf = lds8c((const char*)&Ks[cur][0], koff[ks] + g * 4096);
                    sc[g] = mfma16x16(qf[ks], kf, sc[g]);
                }
            }
            if (kb + 63 <= q0w) {
#pragma unroll
                for (int g = 0; g < 4; ++g)
#pragma unroll
                    for (int r = 0; r < 4; ++r) {
                        const float p = exp2f(sc[g][r] * scale2);
                        lpart[r] += p;
                        P[(quad * 4 + r) * 72 + g * 16 + l16] = bf16bits(p);
                    }
            } else {
#pragma unroll
                for (int g = 0; g < 4; ++g)
#pragma unroll
                    for (int r = 0; r < 4; ++r) {
                        const int row = q0w + quad * 4 + r;
                        const float a = (kb + g * 16 + l16 <= row)
                                        ? sc[g][r] * scale2 : -INFINITY;
                        const float p = exp2f(a);
                        lpart[r] += p;
                        P[(quad * 4 + r) * 72 + g * 16 + l16] = bf16bits(p);
                    }
            }
            __builtin_amdgcn_sched_barrier(0);
            bf16x8 af0 = *(const bf16x8*)(P + l16 * 72 + quad * 8);
            bf16x8 af1 = *(const bf16x8*)(P + l16 * 72 + 32 + quad * 8);
#pragma unroll
            for (int j = 0; j < 8; ++j) {
                bf16x8 vf0 = lds8c((const char*)&Vs[cur][0], (j * 16 + l16) * 128 + vkey[0]);
                bf16x8 vf1 = lds8c((const char*)&Vs[cur][0], (j * 16 + l16) * 128 + vkey[1]);
                o[j] = mfma16x16(af0, vf0, o[j]);
                o[j] = mfma16x16(af1, vf1, o[j]);
            }
            __builtin_amdgcn_sched_barrier(0);
        }
        __syncthreads();   // drains prefetch vmcnt + cur LDS reads
    }

    float invl[4];
#pragma unroll
    for (int r = 0; r < 4; ++r) {
        float s = lpart[r];
#pragma unroll
        for (int off = 1; off < 16; off <<= 1)
            s += __shfl_xor(s, off, 16);
        invl[r] = 1.0f / s;
    }

    const int b = bh >> 4;
    const int h = bh & 15;
#pragma unroll
    for (int j = 0; j < 8; ++j) {
#pragma unroll
        for (int r = 0; r < 4; ++r) {
            const int t = q0w + quad * 4 + r;
            Y[((size_t)b * Tn + t) * Cn + h * Dn + j * 16 + l16] =
                __float2bfloat16(o[j][r] * invl[r]);
        }
    }
}

// ---------------------------------------------------------------------------
// Output projection, pure bf16 inputs, global_load_lds staging, dbuf.
// out = Yb @ wpb^T + b_proj (fp32 out).
// ---------------------------------------------------------------------------
__global__ __launch_bounds__(256) void proj_gemm_kernel(
    const __hip_bfloat16* __restrict__ Yb,
    const __hip_bfloat16* __restrict__ wpb,
    const float* __restrict__ bias,
    float* __restrict__ out)
{
    __shared__ __align__(16) __hip_bfloat16 As[2][128 * 32];
    __shared__ __align__(16) __hip_bfloat16 Bs[2][128 * 32];
    const int tid  = threadIdx.x;
    const int lane = tid & 63;
    const int wid  = tid >> 6;
    const int quad = lane >> 4;
    const int l16  = lane & 15;
    const int bm = blockIdx.y * 128;
    const int bn = blockIdx.x * 128;
    const int wm = (wid >> 1) * 64;
    const int wn = (wid & 1) * 64;

    const int lr = lane >> 2;
    const int lc = (lane & 3) * 8;
    const int r0 = 32 * wid;
    const __hip_bfloat16* Ag0 = Yb  + (size_t)(bm + r0 + lr) * Cn + lc;
    const __hip_bfloat16* Ag1 = Yb  + (size_t)(bm + r0 + 16 + lr) * Cn + lc;
    const __hip_bfloat16* Bg0 = wpb + (size_t)(bn + r0 + lr) * Cn + lc;
    const __hip_bfloat16* Bg1 = wpb + (size_t)(bn + r0 + 16 + lr) * Cn + lc;
    const int lbase0 = r0 * 32 + lane * 8;
    const int lbase1 = (r0 + 16) * 32 + lane * 8;

    const f32x4 zero = {0.f, 0.f, 0.f, 0.f};
    f32x4 acc[4][4];
#pragma unroll
    for (int i = 0; i < 4; ++i)
#pragma unroll
        for (int j = 0; j < 4; ++j) acc[i][j] = zero;

    stage16(Ag0, &As[0][lbase0]);
    stage16(Ag1, &As[0][lbase1]);
    stage16(Bg0, &Bs[0][lbase0]);
    stage16(Bg1, &Bs[0][lbase1]);
    __syncthreads();

    for (int kt = 0; kt < NKT; ++kt) {
        const int cur = kt & 1;
        if (kt + 1 < NKT) {
            const int kn = (kt + 1) * 32;
            stage16(Ag0 + kn, &As[cur ^ 1][lbase0]);
            stage16(Ag1 + kn, &As[cur ^ 1][lbase1]);
            stage16(Bg0 + kn, &Bs[cur ^ 1][lbase0]);
            stage16(Bg1 + kn, &Bs[cur ^ 1][lbase1]);
        }
        bf16x8 af[4], bfr[4];
#pragma unroll
        for (int i = 0; i < 4; ++i)
            af[i] = load8(&As[cur][(wm + i * 16 + l16) * 32 + quad * 8]);
#pragma unroll
        for (int j = 0; j < 4; ++j)
            bfr[j] = load8(&Bs[cur][(wn + j * 16 + l16) * 32 + quad * 8]);
#pragma unroll
        for (int i = 0; i < 4; ++i)
#pragma unroll
            for (int j = 0; j < 4; ++j)
                acc[i][j] = mfma16x16(af[i], bfr[j], acc[i][j]);
        __syncthreads();
    }

#pragma unroll
    for (int j = 0; j < 4; ++j) {
        const int n = bn + wn + j * 16 + l16;
        const float bv = bias[n];
#pragma unroll
        for (int i = 0; i < 4; ++i) {
#pragma unroll
            for (int r = 0; r < 4; ++r) {
                const int m = bm + wm + i * 16 + quad * 4 + r;
                out[(size_t)m * Cn + n] = acc[i][j][r] + bv;   // fp32 store
            }
        }
    }
}

// ---------------------------------------------------------------------------
extern "C" void kernel_launch(void* const* d_in, const int* in_sizes, int n_in,
                              void* d_out, int out_size, void* d_ws, size_t ws_size,
                              hipStream_t stream)
{
    // All five inputs AND the output are fp32 (verified round 5).
    const float* x      = (const float*)d_in[0];
    const float* w_att  = (const float*)d_in[1];
    const float* b_att  = (const float*)d_in[2];
    const float* w_proj = (const float*)d_in[3];
    const float* b_proj = (const float*)d_in[4];
    float* out = (float*)d_out;

    // Workspace layout (bf16 elements), ~96 MB total:
    //   [Qo per][Ko per][Vt per][xb per | Yb alias][wab 12.58M][wpb 4.19M]
    // xb|wab|wpb are CONTIGUOUS -> single cvt3 launch writes all three.
    const size_t per  = (size_t)BH * Tn * Dn;        // 8,388,608
    const size_t wabN = (size_t)Nqkv * Cn;           // 12,582,912
    __hip_bfloat16* Qo  = (__hip_bfloat16*)d_ws;
    __hip_bfloat16* Ko  = Qo + per;
    __hip_bfloat16* Vt  = Ko + per;
    __hip_bfloat16* xb  = Vt + per;
    __hip_bfloat16* wab = xb + per;
    __hip_bfloat16* wpb = wab + wabN;
    __hip_bfloat16* Yb  = xb;                        // alias (see above)

    const long n0 = (long)Mrows * Cn;                // 8,388,608
    const long n1 = (long)Nqkv * Cn;                 // 12,582,912
    const long n2 = (long)Cn * Cn;                   // 4,194,304

    dim3 blk(256);
    cvt3_kernel<<<dim3((unsigned)((n0 + n1 + n2) / 2048)), blk, 0, stream>>>(
        x, w_att, w_proj, xb, n0, n1);
    qkv_gemm_kernel<<<dim3(Nqkv / 128, Mrows / 128), blk, 0, stream>>>(
        xb, wab, b_att, Qo, Ko, Vt);
    rope_kernel<<<dim3((BH * Tn * 64) / 256), blk, 0, stream>>>(Qo, Ko);
    flash_kernel<<<dim3((Tn / 64) * BH), blk, 0, stream>>>(Qo, Ko, Vt, Yb);
    proj_gemm_kernel<<<dim3(Cn / 128, Mrows / 128), blk, 0, stream>>>(
        Yb, wpb, b_proj, out);
}